// Round 10
// baseline (247.616 us; speedup 1.0000x reference)
//
#include <hip/hip_runtime.h>
#include <cstdint>

#define DIMC 1024
#define NSEQ 2048
#define BATCH 2
#define HEADS 16
#define HD 64
#define MROWS (BATCH * NSEQ) /* 4096 */

typedef unsigned short u16;
typedef unsigned int u32;
typedef __attribute__((ext_vector_type(8))) short bf16x8;
typedef __attribute__((ext_vector_type(4))) float f32x4;

#if __has_builtin(__builtin_amdgcn_exp2f)
#define EXP2(x) __builtin_amdgcn_exp2f(x)
#else
#define EXP2(x) exp2f(x)
#endif

__device__ __forceinline__ u16 f2bf(float f) {
  union { float f; u32 u; } v; v.f = f;
  u32 u = v.u;
  return (u16)((u + 0x7fffu + ((u >> 16) & 1u)) >> 16);
}
__device__ __forceinline__ u32 pack_rne(float a, float b) {
  return (u32)f2bf(a) | ((u32)f2bf(b) << 16);
}
__device__ __forceinline__ u32 pack_trunc(float a, float b) {
  union { float f; u32 u; } x, y; x.f = a; y.f = b;
  return (x.u >> 16) | (y.u & 0xffff0000u);
}
// async global->LDS, 16B per lane. LDS dest must be wave-uniform base + lane*16.
__device__ __forceinline__ void gload_lds16(const void* g, void* l) {
  __builtin_amdgcn_global_load_lds((const __attribute__((address_space(1))) void*)g,
                                   (__attribute__((address_space(3))) void*)l, 16, 0, 0);
}

// ---------------- prep: LayerNorm+cast (wave-per-row) & W transpose+cast --------
// W^T: 64x64 f32 tiles (1024 blocks), float4 coalesced reads, LDS [64][68],
// uint4 16B/lane bf16 stores.
__global__ __launch_bounds__(256)
void prep(const float* __restrict__ q, const float* __restrict__ k,
          const float* __restrict__ v,
          const float* __restrict__ gq, const float* __restrict__ bq,
          const float* __restrict__ gk, const float* __restrict__ bk,
          const float* __restrict__ gv, const float* __restrict__ bv,
          const float* __restrict__ w0, const float* __restrict__ w1,
          const float* __restrict__ w2, const float* __restrict__ w3,
          u16* __restrict__ xn, u16* __restrict__ wtout) {
  __shared__ float tile[64][68];
  int tid = threadIdx.x;
  if (blockIdx.x < 3 * MROWS / 4) {
    int wave = tid >> 6, lane = tid & 63;
    int rowid = blockIdx.x * 4 + wave;
    int tensor = rowid >> 12;
    int r = rowid & 4095;
    const float *src, *g, *b;
    if (tensor == 0)      { src = q; g = gq; b = bq; }
    else if (tensor == 1) { src = k; g = gk; b = bk; }
    else                  { src = v; g = gv; b = bv; }
    src += (size_t)r * DIMC;
    u16* dst = xn + (size_t)tensor * MROWS * DIMC + (size_t)r * DIMC;
    float4 x[4];
    float s = 0.f, s2 = 0.f;
    #pragma unroll
    for (int j = 0; j < 4; ++j) {
      x[j] = ((const float4*)src)[j * 64 + lane];
      s  += x[j].x + x[j].y + x[j].z + x[j].w;
      s2 += x[j].x*x[j].x + x[j].y*x[j].y + x[j].z*x[j].z + x[j].w*x[j].w;
    }
    #pragma unroll
    for (int m = 1; m < 64; m <<= 1) { s += __shfl_xor(s, m); s2 += __shfl_xor(s2, m); }
    float mu  = s * (1.0f / DIMC);
    float var = s2 * (1.0f / DIMC) - mu * mu;
    float inv = rsqrtf(var + 1e-5f);
    #pragma unroll
    for (int j = 0; j < 4; ++j) {
      float4 gg = ((const float4*)g)[j * 64 + lane];
      float4 bb = ((const float4*)b)[j * 64 + lane];
      uint2 o;
      o.x = pack_rne((x[j].x - mu) * inv * gg.x + bb.x, (x[j].y - mu) * inv * gg.y + bb.y);
      o.y = pack_rne((x[j].z - mu) * inv * gg.z + bb.z, (x[j].w - mu) * inv * gg.w + bb.w);
      ((uint2*)dst)[j * 64 + lane] = o;
    }
  } else {
    int blk = blockIdx.x - 3 * MROWS / 4;        // 0..1023
    int widx = blk >> 8, t = blk & 255;          // 4 matrices x 256 tiles
    int ti = t >> 4, tj = t & 15;                // 64-row / 64-col tile coords
    const float* W = (widx == 0) ? w0 : (widx == 1) ? w1 : (widx == 2) ? w2 : w3;
    u16* O = wtout + (size_t)widx * DIMC * DIMC;
    int rr = tid >> 4, cc = tid & 15;
    #pragma unroll
    for (int p = 0; p < 4; ++p) {
      int r = p * 16 + rr;
      float4 x = *(const float4*)(&W[(size_t)(ti * 64 + r) * DIMC + tj * 64 + cc * 4]);
      *(float4*)(&tile[r][cc * 4]) = x;
    }
    __syncthreads();
    int c = tid >> 2, r0 = (tid & 3) * 16;
    #pragma unroll
    for (int s = 0; s < 2; ++s) {
      int rb = r0 + s * 8;
      uint4 y;
      y.x = pack_rne(tile[rb + 0][c], tile[rb + 1][c]);
      y.y = pack_rne(tile[rb + 2][c], tile[rb + 3][c]);
      y.z = pack_rne(tile[rb + 4][c], tile[rb + 5][c]);
      y.w = pack_rne(tile[rb + 6][c], tile[rb + 7][c]);
      *(uint4*)(&O[(size_t)(tj * 64 + c) * DIMC + ti * 64 + rb]) = y;
    }
  }
}

// ---------------- fused QKV projection GEMM (grid.z selects Q/K/V) ----------------
// R10: retiled 128x128 -> 128x64 (the R3/R9 occupancy lever). 1536 blocks =
// 6 blocks/CU = 24 waves/CU (was 768 = 3/CU, latency-bound: MfmaUtil 17%,
// VALUBusy 24%, all pipes idle). LDS 24KB (dbuf As 2x8KB + Bs 2x4KB); z==2
// transpose Ls (64x136 = 17.4KB) overlays the front after the K-loop. Same MFMA
// sequence per output -> bit-identical. Keys PERMUTED within each 32-block in
// vtb (lane-local P in attention, R5-verified).
__global__ __launch_bounds__(256)
void qkv_gemm(const u16* __restrict__ xn, const u16* __restrict__ wt,
              const float* __restrict__ bq, const float* __restrict__ bk,
              const float* __restrict__ bv,
              float* __restrict__ out, u16* __restrict__ qh,
              u16* __restrict__ khb, u16* __restrict__ vtb) {
  __shared__ u16 smem[12288];                // 24KB
  u16* As0 = smem;                           // 128*32 (8KB)
  u16* Bs0 = smem + 4096;                    // 64*32  (4KB)
  u16* As1 = smem + 6144;
  u16* Bs1 = smem + 10240;
  u16* Ls  = smem;                           // transpose tile [c][m] stride 136
  const int z = blockIdx.z;
  const u16* A  = xn + (size_t)z * MROWS * DIMC;
  const u16* Bt = wt + (size_t)z * DIMC * DIMC;
  const float* bias = (z == 0) ? bq : (z == 1) ? bk : bv;
  const int bm = blockIdx.x, bn = blockIdx.y;
  const int tid = threadIdx.x;
  const int wave = tid >> 6, lane = tid & 63;
  const int wm = (wave & 1) * 64, wn = (wave >> 1) * 32;
  const int row = lane & 15, quad = lane >> 4;
  const float QSCL = 0.18033688011112042f;  // 0.125 * log2(e)
  // per-thread staging cursors (advance +32 per K-step)
  const int e0 = tid * 8, e1 = 2048 + tid * 8;   // A: 4096 elems, B: 2048 elems
  const u16* pa0 = A  + (size_t)(bm * 128 + (e0 >> 5)) * DIMC + (e0 & 31);
  const u16* pa1 = A  + (size_t)(bm * 128 + (e1 >> 5)) * DIMC + (e1 & 31);
  const u16* pb0 = Bt + (size_t)(bn * 64  + (e0 >> 5)) * DIMC + (e0 & 31);
  f32x4 acc[4][2] = {};
  // prologue: stage k0=0 into buf0
  gload_lds16(pa0, As0 + e0);
  gload_lds16(pa1, As0 + e1);
  gload_lds16(pb0, Bs0 + e0);
  pa0 += 32; pa1 += 32; pb0 += 32;
  __syncthreads();
  for (int k0 = 0; k0 < DIMC; k0 += 32) {
    const int cur = (k0 >> 5) & 1;
    u16* Asc = cur ? As1 : As0;
    u16* Bsc = cur ? Bs1 : Bs0;
    if (k0 + 32 < DIMC) {              // issue next tile BEFORE compute
      u16* Asn = cur ? As0 : As1;
      u16* Bsn = cur ? Bs0 : Bs1;
      gload_lds16(pa0, Asn + e0);
      gload_lds16(pa1, Asn + e1);
      gload_lds16(pb0, Bsn + e0);
      pa0 += 32; pa1 += 32; pb0 += 32;
    }
    bf16x8 a[4], b[2];
    #pragma unroll
    for (int i = 0; i < 4; ++i)
      a[i] = *(const bf16x8*)(&Asc[(wm + i * 16 + row) * 32 + quad * 8]);
    #pragma unroll
    for (int j = 0; j < 2; ++j)
      b[j] = *(const bf16x8*)(&Bsc[(wn + j * 16 + row) * 32 + quad * 8]);
    #pragma unroll
    for (int i = 0; i < 4; ++i)
      #pragma unroll
      for (int j = 0; j < 2; ++j)
        acc[i][j] = __builtin_amdgcn_mfma_f32_16x16x32_bf16(a[i], b[j], acc[i][j], 0, 0, 0);
    __syncthreads();                   // waves done with buf[cur]; next loads drained
  }
  #pragma unroll
  for (int i = 0; i < 4; ++i) {
    #pragma unroll
    for (int j = 0; j < 2; ++j) {
      float val[4];
      #pragma unroll
      for (int r = 0; r < 4; ++r) {
        int m = bm * 128 + wm + i * 16 + quad * 4 + r;
        int c = bn * 64 + wn + j * 16 + row;
        val[r] = acc[i][j][r] + bias[c];
        int b_ = m >> 11, n = m & 2047, h = c >> 6, d = c & 63;
        int bh = b_ * HEADS + h;
        size_t hidx = ((size_t)bh * NSEQ + n) * HD + d;
        if (z == 0) {
          qh[hidx] = f2bf(val[r] * QSCL);   // pre-scaled for attention exp2
        } else {
          out[(size_t)z * MROWS * DIMC + hidx] = val[r];
          if (z == 1) khb[hidx] = f2bf(val[r]);
        }
      }
      if (z == 2) {
        int ct = wn + j * 16 + row;          // 0..63 (col within tile)
        int mt = wm + i * 16 + quad * 4;     // 0..127 (m within tile)
        u32* L = (u32*)(&Ls[ct * 136 + mt]);
        L[0] = pack_rne(val[0], val[1]);
        L[1] = pack_rne(val[2], val[3]);
      }
    }
  }
  if (z == 2) {
    __syncthreads();
    int b_ = (bm * 128) >> 11;
    int nbase = (bm * 128) & 2047;
    #pragma unroll
    for (int it = 0; it < 4; ++it) {        // 64 ct x 16 ch = 1024 entries
      int idx = it * 256 + tid;
      int ct = idx >> 4, ch = idx & 15;     // ct = c within tile, ch = 8-m chunk
      uint4 y = *(const uint4*)(&Ls[ct * 136 + ch * 8]);
      int c = bn * 64 + ct;
      int h = c >> 6, d = c & 63;
      size_t rowb = ((size_t)(b_ * HEADS + h) * HD + d) * NSEQ;
      int K0 = nbase + ch * 8;              // 8 consecutive keys, K0 % 8 == 0
      int d1 = (K0 & ~31) + ((K0 & 8) ? 16 : 0) + ((K0 & 16) ? 4 : 0);
      uint2 lo; lo.x = y.x; lo.y = y.y;     // keys K0..K0+3  -> slots d1..d1+3
      uint2 hi; hi.x = y.z; hi.y = y.w;     // keys K0+4..K0+7-> slots d1+8..d1+11
      *(uint2*)(&vtb[rowb + d1])     = lo;
      *(uint2*)(&vtb[rowb + d1 + 8]) = hi;
    }
  }
}

// ---------------- output projection GEMM (64x64 tile, dbuf, 4 blocks/CU) --------
__global__ __launch_bounds__(256)
void out_gemm(const u16* __restrict__ A, const u16* __restrict__ Bt,
              const float* __restrict__ bias, float* __restrict__ outf) {
  __shared__ u16 As[2][64 * 32];
  __shared__ u16 Bs[2][64 * 32];
  const int bm = blockIdx.x, bn = blockIdx.y;
  const int tid = threadIdx.x;
  const int wave = tid >> 6, lane = tid & 63;
  const int wm = (wave & 1) * 32, wn = (wave >> 1) * 32;
  const int row = lane & 15, quad = lane >> 4;
  const int e = tid * 8;
  const u16* pa = A  + (size_t)(bm * 64 + (e >> 5)) * DIMC + (e & 31);
  const u16* pb = Bt + (size_t)(bn * 64 + (e >> 5)) * DIMC + (e & 31);
  f32x4 acc[2][2] = {};
  gload_lds16(pa, &As[0][e]);
  gload_lds16(pb, &Bs[0][e]);
  pa += 32; pb += 32;
  __syncthreads();
  for (int k0 = 0; k0 < DIMC; k0 += 32) {
    const int cur = (k0 >> 5) & 1;
    if (k0 + 32 < DIMC) {              // issue next tile BEFORE compute
      gload_lds16(pa, &As[cur ^ 1][e]);
      gload_lds16(pb, &Bs[cur ^ 1][e]);
      pa += 32; pb += 32;
    }
    bf16x8 a[2], b[2];
    #pragma unroll
    for (int i = 0; i < 2; ++i)
      a[i] = *(const bf16x8*)(&As[cur][(wm + i * 16 + row) * 32 + quad * 8]);
    #pragma unroll
    for (int j = 0; j < 2; ++j)
      b[j] = *(const bf16x8*)(&Bs[cur][(wn + j * 16 + row) * 32 + quad * 8]);
    #pragma unroll
    for (int i = 0; i < 2; ++i)
      #pragma unroll
      for (int j = 0; j < 2; ++j)
        acc[i][j] = __builtin_amdgcn_mfma_f32_16x16x32_bf16(a[i], b[j], acc[i][j], 0, 0, 0);
    __syncthreads();
  }
  #pragma unroll
  for (int i = 0; i < 2; ++i)
    #pragma unroll
    for (int j = 0; j < 2; ++j)
      #pragma unroll
      for (int r = 0; r < 4; ++r) {
        int m = bm * 64 + wm + i * 16 + quad * 4 + r;
        int c = bn * 64 + wn + j * 16 + row;
        outf[(size_t)m * DIMC + c] = acc[i][j][r] + bias[c];
      }
}

// ---------------- fused flash attention, IN-BLOCK KEY-SPLIT x2 (R9, proven) -----
// 512 threads / 8 waves; waves 0-3 keys 0-1023, waves 4-7 keys 1024-2047, same
// 128 q-rows. 64KB LDS -> 2 blocks/CU, 4096 waves = 4/SIMD. LDS combine pass.
__global__ __launch_bounds__(512)
void attn_fused(const u16* __restrict__ qh, const u16* __restrict__ kh,
                const u16* __restrict__ vt, u16* __restrict__ ao) {
  __shared__ u16 smem[32768];        // 64KB: Ks[half][buf] 4x8KB | Vs[half][buf] 4x8KB
  u16* KS = smem;                    // KS + ((half*2+buf)*4096)
  u16* VS = smem + 16384;
  const int flat = blockIdx.x;
  const int bh = (flat & 7) * 4 + ((flat >> 3) & 3);
  const int qtile = flat >> 5;       // 0..15, 128 q-rows each
  const int b = bh >> 4, h = bh & 15;
  const int tid = threadIdx.x;
  const int wave = tid >> 6, lane = tid & 63;
  const int half = wave >> 2;        // key-split half: 0 or 1
  const int wq = wave & 3;           // q-subwave within half
  const int qi = lane & 15, quad = lane >> 4;
  const int sw = qi & 7;
  const size_t base = (size_t)bh * NSEQ * HD;
  bf16x8 qf[2][2];                   // [q-subtile][d-half]
  #pragma unroll
  for (int qt = 0; qt < 2; ++qt) {
    int qrow = qtile * 128 + wq * 32 + qt * 16 + qi;
    #pragma unroll
    for (int dh = 0; dh < 2; ++dh)
      qf[qt][dh] = *(const bf16x8*)(&qh[base + (size_t)qrow * HD + dh * 32 + quad * 8]);
  }
  // per-thread staging offsets within this half (256 threads per half)
  const int htid = tid & 255;
  const int rk0 = htid >> 3, ck0 = htid & 7;        // chunk rows 0..31
  const int rk1 = 32 + (htid >> 3);                 // chunk rows 32..63
  const int ko0 = rk0 * HD + ((ck0 ^ (rk0 & 7)) * 8);
  const int ko1 = rk1 * HD + ((ck0 ^ (rk1 & 7)) * 8);
  const int vo0 = rk0 * NSEQ + ((ck0 ^ (rk0 & 7)) * 8);
  const int vo1 = rk1 * NSEQ + ((ck0 ^ (rk1 & 7)) * 8);
  const int ldso = htid * 8;
  u16* Kh = KS + half * 8192;        // this half's two buffers
  u16* Vh = VS + half * 8192;
  const u16* kcur = kh + base + (size_t)(half * 1024) * HD;
  const u16* vcur = vt + base + half * 1024;
  // prologue: stage this half's tile 0 into buffer 0
  gload_lds16(kcur + ko0, Kh + ldso);
  gload_lds16(kcur + ko1, Kh + 2048 + ldso);
  gload_lds16(vcur + vo0, Vh + ldso);
  gload_lds16(vcur + vo1, Vh + 2048 + ldso);
  kcur += 64 * HD; vcur += 64;
  __syncthreads();                    // drains vmcnt -> tile 0 resident
  float li0 = 0.f, li1 = 0.f;
  f32x4 oacc[2][4] = {};
  for (int t = 0; t < 16; ++t) {      // 16 x 64-key tiles per half
    const int cur = t & 1;
    if (t < 15) {                     // issue next tile's loads BEFORE compute
      u16* kd = Kh + (cur ^ 1) * 4096;
      u16* vd = Vh + (cur ^ 1) * 4096;
      gload_lds16(kcur + ko0, kd + ldso);
      gload_lds16(kcur + ko1, kd + 2048 + ldso);
      gload_lds16(vcur + vo0, vd + ldso);
      gload_lds16(vcur + vo1, vd + 2048 + ldso);
      kcur += 64 * HD; vcur += 64;
    }
    const u16* Kb = Kh + cur * 4096;
    const u16* Vb = Vh + cur * 4096;
    #pragma unroll
    for (int kc = 0; kc < 2; ++kc) {
      const u16* kr0 = &Kb[((kc * 2) * 16 + qi) * 64];
      const u16* kr1 = &Kb[((kc * 2 + 1) * 16 + qi) * 64];
      bf16x8 ka0 = *(const bf16x8*)(&kr0[(quad ^ sw) * 8]);
      bf16x8 ka1 = *(const bf16x8*)(&kr0[((4 + quad) ^ sw) * 8]);
      bf16x8 kb0 = *(const bf16x8*)(&kr1[(quad ^ sw) * 8]);
      bf16x8 kb1 = *(const bf16x8*)(&kr1[((4 + quad) ^ sw) * 8]);
      bf16x8 vf[4];
      #pragma unroll
      for (int dt = 0; dt < 4; ++dt)
        vf[dt] = *(const bf16x8*)(&Vb[(dt * 16 + qi) * 64 + ((kc * 4 + quad) ^ sw) * 8]);
      f32x4 s00 = {}, s01 = {}, s10 = {}, s11 = {};   // [q-subtile][key-tile]
      __builtin_amdgcn_s_setprio(1);
      s00 = __builtin_amdgcn_mfma_f32_16x16x32_bf16(ka0, qf[0][0], s00, 0, 0, 0);
      s00 = __builtin_amdgcn_mfma_f32_16x16x32_bf16(ka1, qf[0][1], s00, 0, 0, 0);
      s01 = __builtin_amdgcn_mfma_f32_16x16x32_bf16(kb0, qf[0][0], s01, 0, 0, 0);
      s01 = __builtin_amdgcn_mfma_f32_16x16x32_bf16(kb1, qf[0][1], s01, 0, 0, 0);
      s10 = __builtin_amdgcn_mfma_f32_16x16x32_bf16(ka0, qf[1][0], s10, 0, 0, 0);
      s10 = __builtin_amdgcn_mfma_f32_16x16x32_bf16(ka1, qf[1][1], s10, 0, 0, 0);
      s11 = __builtin_amdgcn_mfma_f32_16x16x32_bf16(kb0, qf[1][0], s11, 0, 0, 0);
      s11 = __builtin_amdgcn_mfma_f32_16x16x32_bf16(kb1, qf[1][1], s11, 0, 0, 0);
      __builtin_amdgcn_s_setprio(0);
      float a0 = EXP2(s00[0]), a1 = EXP2(s00[1]), a2 = EXP2(s00[2]), a3 = EXP2(s00[3]);
      float a4 = EXP2(s01[0]), a5 = EXP2(s01[1]), a6 = EXP2(s01[2]), a7 = EXP2(s01[3]);
      float b0 = EXP2(s10[0]), b1 = EXP2(s10[1]), b2 = EXP2(s10[2]), b3 = EXP2(s10[3]);
      float b4 = EXP2(s11[0]), b5 = EXP2(s11[1]), b6 = EXP2(s11[2]), b7 = EXP2(s11[3]);
      li0 += ((a0 + a1) + (a2 + a3)) + ((a4 + a5) + (a6 + a7));
      li1 += ((b0 + b1) + (b2 + b3)) + ((b4 + b5) + (b6 + b7));
      union { bf16x8 v; u32 u[4]; } pu0, pu1;
      pu0.u[0] = pack_trunc(a0, a1); pu0.u[1] = pack_trunc(a2, a3);
      pu0.u[2] = pack_trunc(a4, a5); pu0.u[3] = pack_trunc(a6, a7);
      pu1.u[0] = pack_trunc(b0, b1); pu1.u[1] = pack_trunc(b2, b3);
      pu1.u[2] = pack_trunc(b4, b5); pu1.u[3] = pack_trunc(b6, b7);
      __builtin_amdgcn_s_setprio(1);
      #pragma unroll
      for (int dt = 0; dt < 4; ++dt) {
        oacc[0][dt] = __builtin_amdgcn_mfma_f32_16x16x32_bf16(vf[dt], pu0.v, oacc[0][dt], 0, 0, 0);
        oacc[1][dt] = __builtin_amdgcn_mfma_f32_16x16x32_bf16(vf[dt], pu1.v, oacc[1][dt], 0, 0, 0);
      }
      __builtin_amdgcn_s_setprio(0);
    }
    __syncthreads();                  // all waves done with buf[cur]; next loads drained
  }
  // ---- combine halves through LDS (SoA: comp-major, stride-1 lanes, no conflicts)
  float* cb = (float*)smem;           // 34 comps x 256 idx x 4B = 34.8KB (staging done)
  const int idx = wq * 64 + lane;
  if (half == 1) {
    #pragma unroll
    for (int qt = 0; qt < 2; ++qt)
      #pragma unroll
      for (int dt = 0; dt < 4; ++dt)
        #pragma unroll
        for (int r = 0; r < 4; ++r)
          cb[(qt * 16 + dt * 4 + r) * 256 + idx] = oacc[qt][dt][r];
    cb[32 * 256 + idx] = li0;
    cb[33 * 256 + idx] = li1;
  }
  __syncthreads();
  if (half == 0) {
    #pragma unroll
    for (int qt = 0; qt < 2; ++qt)
      #pragma unroll
      for (int dt = 0; dt < 4; ++dt)
        #pragma unroll
        for (int r = 0; r < 4; ++r)
          oacc[qt][dt][r] += cb[(qt * 16 + dt * 4 + r) * 256 + idx];
    li0 += cb[32 * 256 + idx];
    li1 += cb[33 * 256 + idx];
    // deferred cross-lane softmax-denominator reduction
    li0 += __shfl_xor(li0, 16); li0 += __shfl_xor(li0, 32);
    li1 += __shfl_xor(li1, 16); li1 += __shfl_xor(li1, 32);
    #pragma unroll
    for (int qt = 0; qt < 2; ++qt) {
      float inv = 1.0f / (qt == 0 ? li0 : li1);
      int token = b * NSEQ + qtile * 128 + wq * 32 + qt * 16 + qi;
      #pragma unroll
      for (int dt = 0; dt < 4; ++dt) {
        int col = h * 64 + dt * 16 + quad * 4;
        *(u32*)(&ao[(size_t)token * DIMC + col]) =
            pack_rne(oacc[qt][dt][0] * inv, oacc[qt][dt][1] * inv);
        *(u32*)(&ao[(size_t)token * DIMC + col + 2]) =
            pack_rne(oacc[qt][dt][2] * inv, oacc[qt][dt][3] * inv);
      }
    }
  }
}

extern "C" void kernel_launch(void* const* d_in, const int* in_sizes, int n_in,
                              void* d_out, int out_size, void* d_ws, size_t ws_size,
                              hipStream_t stream) {
  const float* q    = (const float*)d_in[0];
  const float* k    = (const float*)d_in[1];
  const float* v    = (const float*)d_in[2];
  const float* gq   = (const float*)d_in[3];
  const float* bqln = (const float*)d_in[4];
  const float* gk   = (const float*)d_in[5];
  const float* bkln = (const float*)d_in[6];
  const float* gv   = (const float*)d_in[7];
  const float* bvln = (const float*)d_in[8];
  const float* Wq   = (const float*)d_in[9];
  const float* bq   = (const float*)d_in[10];
  const float* Wk   = (const float*)d_in[11];
  const float* bk   = (const float*)d_in[12];
  const float* Wv   = (const float*)d_in[13];
  const float* bv   = (const float*)d_in[14];
  const float* Wp   = (const float*)d_in[15];
  const float* bp   = (const float*)d_in[16];
  float* out = (float*)d_out;

  char* ws = (char*)d_ws;
  u16* xn  = (u16*)(ws);                          // 3 x 4096x1024 bf16 (24MB)
  u16* wt  = (u16*)(ws + (size_t)25165824);       // 4 x 1024x1024 bf16 (8MB)
  u16* qh  = (u16*)(ws + (size_t)33554432);       // [bh][n][d] bf16 (pre-scaled)
  u16* khb = (u16*)(ws + (size_t)41943040);       // [bh][n][d] bf16
  u16* ao  = (u16*)(ws + (size_t)50331648);       // [token][1024] bf16
  // V^T lives in the output-0 region of d_out (16.78 MB, exactly fits);
  // out_gemm overwrites it afterwards.
  u16* vtb = (u16*)d_out;                         // [bh][d][n-permuted] bf16

  const size_t WEL = (size_t)DIMC * DIMC;

  prep<<<3 * MROWS / 4 + 1024, 256, 0, stream>>>(q, k, v, gq, bqln, gk, bkln, gv, bvln,
                                                 Wq, Wk, Wv, Wp, xn, wt);
  qkv_gemm<<<dim3(MROWS / 128, DIMC / 64, 3), 256, 0, stream>>>(
      xn, wt, bq, bk, bv, out, qh, khb, vtb);
  attn_fused<<<dim3((NSEQ / 128) * BATCH * HEADS), 512, 0, stream>>>(qh, khb, vtb, ao);
  out_gemm<<<dim3(MROWS / 64, DIMC / 64), 256, 0, stream>>>(ao, wt + 3 * WEL, bp, out);
}

// Round 11
// 242.325 us; speedup vs baseline: 1.0218x; 1.0218x over previous
//
#include <hip/hip_runtime.h>
#include <cstdint>

#define DIMC 1024
#define NSEQ 2048
#define BATCH 2
#define HEADS 16
#define HD 64
#define MROWS (BATCH * NSEQ) /* 4096 */

typedef unsigned short u16;
typedef unsigned int u32;
typedef __attribute__((ext_vector_type(8))) short bf16x8;
typedef __attribute__((ext_vector_type(4))) float f32x4;

#if __has_builtin(__builtin_amdgcn_exp2f)
#define EXP2(x) __builtin_amdgcn_exp2f(x)
#else
#define EXP2(x) exp2f(x)
#endif

__device__ __forceinline__ u16 f2bf(float f) {
  union { float f; u32 u; } v; v.f = f;
  u32 u = v.u;
  return (u16)((u + 0x7fffu + ((u >> 16) & 1u)) >> 16);
}
__device__ __forceinline__ u32 pack_rne(float a, float b) {
  return (u32)f2bf(a) | ((u32)f2bf(b) << 16);
}
__device__ __forceinline__ u32 pack_trunc(float a, float b) {
  union { float f; u32 u; } x, y; x.f = a; y.f = b;
  return (x.u >> 16) | (y.u & 0xffff0000u);
}
// async global->LDS, 16B per lane. LDS dest must be wave-uniform base + lane*16.
__device__ __forceinline__ void gload_lds16(const void* g, void* l) {
  __builtin_amdgcn_global_load_lds((const __attribute__((address_space(1))) void*)g,
                                   (__attribute__((address_space(3))) void*)l, 16, 0, 0);
}

// ---------------- prep: LayerNorm+cast (wave-per-row) & W transpose+cast --------
__global__ __launch_bounds__(256)
void prep(const float* __restrict__ q, const float* __restrict__ k,
          const float* __restrict__ v,
          const float* __restrict__ gq, const float* __restrict__ bq,
          const float* __restrict__ gk, const float* __restrict__ bk,
          const float* __restrict__ gv, const float* __restrict__ bv,
          const float* __restrict__ w0, const float* __restrict__ w1,
          const float* __restrict__ w2, const float* __restrict__ w3,
          u16* __restrict__ xn, u16* __restrict__ wtout) {
  __shared__ float tile[64][68];
  int tid = threadIdx.x;
  if (blockIdx.x < 3 * MROWS / 4) {
    int wave = tid >> 6, lane = tid & 63;
    int rowid = blockIdx.x * 4 + wave;
    int tensor = rowid >> 12;
    int r = rowid & 4095;
    const float *src, *g, *b;
    if (tensor == 0)      { src = q; g = gq; b = bq; }
    else if (tensor == 1) { src = k; g = gk; b = bk; }
    else                  { src = v; g = gv; b = bv; }
    src += (size_t)r * DIMC;
    u16* dst = xn + (size_t)tensor * MROWS * DIMC + (size_t)r * DIMC;
    float4 x[4];
    float s = 0.f, s2 = 0.f;
    #pragma unroll
    for (int j = 0; j < 4; ++j) {
      x[j] = ((const float4*)src)[j * 64 + lane];
      s  += x[j].x + x[j].y + x[j].z + x[j].w;
      s2 += x[j].x*x[j].x + x[j].y*x[j].y + x[j].z*x[j].z + x[j].w*x[j].w;
    }
    #pragma unroll
    for (int m = 1; m < 64; m <<= 1) { s += __shfl_xor(s, m); s2 += __shfl_xor(s2, m); }
    float mu  = s * (1.0f / DIMC);
    float var = s2 * (1.0f / DIMC) - mu * mu;
    float inv = rsqrtf(var + 1e-5f);
    #pragma unroll
    for (int j = 0; j < 4; ++j) {
      float4 gg = ((const float4*)g)[j * 64 + lane];
      float4 bb = ((const float4*)b)[j * 64 + lane];
      uint2 o;
      o.x = pack_rne((x[j].x - mu) * inv * gg.x + bb.x, (x[j].y - mu) * inv * gg.y + bb.y);
      o.y = pack_rne((x[j].z - mu) * inv * gg.z + bb.z, (x[j].w - mu) * inv * gg.w + bb.w);
      ((uint2*)dst)[j * 64 + lane] = o;
    }
  } else {
    int blk = blockIdx.x - 3 * MROWS / 4;        // 0..1023
    int widx = blk >> 8, t = blk & 255;          // 4 matrices x 256 tiles
    int ti = t >> 4, tj = t & 15;                // 64-row / 64-col tile coords
    const float* W = (widx == 0) ? w0 : (widx == 1) ? w1 : (widx == 2) ? w2 : w3;
    u16* O = wtout + (size_t)widx * DIMC * DIMC;
    int rr = tid >> 4, cc = tid & 15;
    #pragma unroll
    for (int p = 0; p < 4; ++p) {
      int r = p * 16 + rr;
      float4 x = *(const float4*)(&W[(size_t)(ti * 64 + r) * DIMC + tj * 64 + cc * 4]);
      *(float4*)(&tile[r][cc * 4]) = x;
    }
    __syncthreads();
    int c = tid >> 2, r0 = (tid & 3) * 16;
    #pragma unroll
    for (int s = 0; s < 2; ++s) {
      int rb = r0 + s * 8;
      uint4 y;
      y.x = pack_rne(tile[rb + 0][c], tile[rb + 1][c]);
      y.y = pack_rne(tile[rb + 2][c], tile[rb + 3][c]);
      y.z = pack_rne(tile[rb + 4][c], tile[rb + 5][c]);
      y.w = pack_rne(tile[rb + 6][c], tile[rb + 7][c]);
      *(uint4*)(&O[(size_t)(tj * 64 + c) * DIMC + ti * 64 + rb]) = y;
    }
  }
}

// ---------------- fused QKV projection GEMM (grid.z selects Q/K/V) ----------------
// R11: 128x128 tile, 64x64 per wave (0.5 ds_reads/MFMA — best ratio), dbuf,
// PAIR-ROW XOR-SWIZZLED LDS (attn's proven zero-conflict geometry): LDS is
// [64 prows][64 elems]; slot q of prow p holds global (row=2p+(u>>2), colgrp=u&3)
// with u = q ^ (p&7). global_load_lds stays linear; the permutation is applied to
// the per-lane GLOBAL source address (rule: both-sides-or-neither). Fragment reads
// invert the map -> every 8-lane p-group covers all 32 banks once -> 0 conflicts.
// Data->lane mapping of each MFMA operand unchanged -> bit-identical results.
// z==2 epilogue: keys PERMUTED within each 32-block in vtb (lane-local P in attn).
__global__ __launch_bounds__(256)
void qkv_gemm(const u16* __restrict__ xn, const u16* __restrict__ wt,
              const float* __restrict__ bq, const float* __restrict__ bk,
              const float* __restrict__ bv,
              float* __restrict__ out, u16* __restrict__ qh,
              u16* __restrict__ khb, u16* __restrict__ vtb) {
  __shared__ u16 smem[128 * 136];           // 34.8 KB; front 32KB = dbuf As/Bs
  u16* As0 = smem;                           // 4096 elems (8KB) [64][64] pair-row
  u16* Bs0 = smem + 4096;
  u16* As1 = smem + 8192;
  u16* Bs1 = smem + 12288;
  u16* Ls  = smem;                           // transpose tile [c][m] stride 136
  const int z = blockIdx.z;
  const u16* A  = xn + (size_t)z * MROWS * DIMC;
  const u16* Bt = wt + (size_t)z * DIMC * DIMC;
  const float* bias = (z == 0) ? bq : (z == 1) ? bk : bv;
  const int bm = blockIdx.x, bn = blockIdx.y;
  const int tid = threadIdx.x;
  const int wave = tid >> 6, lane = tid & 63;
  const int wm = (wave & 1) * 64, wn = (wave >> 1) * 64;
  const int row = lane & 15, quad = lane >> 4;
  const float QSCL = 0.18033688011112042f;  // 0.125 * log2(e)
  // staging source decode for LDS elem offsets e0 = tid*8, e1 = 2048+tid*8:
  //   p = e>>6, q = (e>>3)&7, u = q^(p&7), srow = 2p+(u>>2), scg = u&3
  const int e0 = tid * 8, e1 = 2048 + tid * 8;
  const int p0_ = e0 >> 6, u0_ = ((e0 >> 3) & 7) ^ (p0_ & 7);
  const int p1_ = e1 >> 6, u1_ = ((e1 >> 3) & 7) ^ (p1_ & 7);
  const int sr0 = 2 * p0_ + (u0_ >> 2), sc0 = (u0_ & 3) * 8;
  const int sr1 = 2 * p1_ + (u1_ >> 2), sc1 = (u1_ & 3) * 8;
  const u16* pa0 = A  + (size_t)(bm * 128 + sr0) * DIMC + sc0;
  const u16* pa1 = A  + (size_t)(bm * 128 + sr1) * DIMC + sc1;
  const u16* pb0 = Bt + (size_t)(bn * 128 + sr0) * DIMC + sc0;
  const u16* pb1 = Bt + (size_t)(bn * 128 + sr1) * DIMC + sc1;
  // fragment read offsets (elems): R = w? + i*16 + row; p = R>>1;
  //   off = p*64 + ((((R&1)<<2)|quad) ^ (p&7))*8
  int aoff[4], boff[4];
  #pragma unroll
  for (int i = 0; i < 4; ++i) {
    int Ra = wm + i * 16 + row, Pa = Ra >> 1;
    aoff[i] = Pa * 64 + (((((Ra & 1) << 2) | quad) ^ (Pa & 7)) * 8);
    int Rb = wn + i * 16 + row, Pb = Rb >> 1;
    boff[i] = Pb * 64 + (((((Rb & 1) << 2) | quad) ^ (Pb & 7)) * 8);
  }
  f32x4 acc[4][4] = {};
  // prologue: stage k0=0 into buf0
  gload_lds16(pa0, As0 + e0); gload_lds16(pa1, As0 + e1);
  gload_lds16(pb0, Bs0 + e0); gload_lds16(pb1, Bs0 + e1);
  pa0 += 32; pa1 += 32; pb0 += 32; pb1 += 32;
  __syncthreads();
  for (int k0 = 0; k0 < DIMC; k0 += 32) {
    const int cur = (k0 >> 5) & 1;
    u16* Asc = cur ? As1 : As0;
    u16* Bsc = cur ? Bs1 : Bs0;
    if (k0 + 32 < DIMC) {              // issue next tile BEFORE compute
      u16* Asn = cur ? As0 : As1;
      u16* Bsn = cur ? Bs0 : Bs1;
      gload_lds16(pa0, Asn + e0); gload_lds16(pa1, Asn + e1);
      gload_lds16(pb0, Bsn + e0); gload_lds16(pb1, Bsn + e1);
      pa0 += 32; pa1 += 32; pb0 += 32; pb1 += 32;
    }
    bf16x8 a[4], b[4];
    #pragma unroll
    for (int i = 0; i < 4; ++i)
      a[i] = *(const bf16x8*)(&Asc[aoff[i]]);
    #pragma unroll
    for (int j = 0; j < 4; ++j)
      b[j] = *(const bf16x8*)(&Bsc[boff[j]]);
    #pragma unroll
    for (int i = 0; i < 4; ++i)
      #pragma unroll
      for (int j = 0; j < 4; ++j)
        acc[i][j] = __builtin_amdgcn_mfma_f32_16x16x32_bf16(a[i], b[j], acc[i][j], 0, 0, 0);
    __syncthreads();                   // waves done with buf[cur]; next loads drained
  }
  #pragma unroll
  for (int i = 0; i < 4; ++i) {
    #pragma unroll
    for (int j = 0; j < 4; ++j) {
      float val[4];
      #pragma unroll
      for (int r = 0; r < 4; ++r) {
        int m = bm * 128 + wm + i * 16 + quad * 4 + r;
        int c = bn * 128 + wn + j * 16 + row;
        val[r] = acc[i][j][r] + bias[c];
        int b_ = m >> 11, n = m & 2047, h = c >> 6, d = c & 63;
        int bh = b_ * HEADS + h;
        size_t hidx = ((size_t)bh * NSEQ + n) * HD + d;
        if (z == 0) {
          qh[hidx] = f2bf(val[r] * QSCL);   // pre-scaled for attention exp2
        } else {
          out[(size_t)z * MROWS * DIMC + hidx] = val[r];
          if (z == 1) khb[hidx] = f2bf(val[r]);
        }
      }
      if (z == 2) {
        int ct = wn + j * 16 + row;
        int mt = wm + i * 16 + quad * 4;
        u32* L = (u32*)(&Ls[ct * 136 + mt]);
        L[0] = pack_rne(val[0], val[1]);
        L[1] = pack_rne(val[2], val[3]);
      }
    }
  }
  if (z == 2) {
    __syncthreads();
    int b_ = (bm * 128) >> 11;
    int nbase = (bm * 128) & 2047;
    #pragma unroll
    for (int it = 0; it < 8; ++it) {
      int idx = it * 256 + tid;
      int ct = idx >> 4, ch = idx & 15;     // ct = c within tile, ch = 8-m chunk
      uint4 y = *(const uint4*)(&Ls[ct * 136 + ch * 8]);
      int c = bn * 128 + ct;
      int h = c >> 6, d = c & 63;
      size_t rowb = ((size_t)(b_ * HEADS + h) * HD + d) * NSEQ;
      int K0 = nbase + ch * 8;              // 8 consecutive keys, K0 % 8 == 0
      int d1 = (K0 & ~31) + ((K0 & 8) ? 16 : 0) + ((K0 & 16) ? 4 : 0);
      uint2 lo; lo.x = y.x; lo.y = y.y;     // keys K0..K0+3  -> slots d1..d1+3
      uint2 hi; hi.x = y.z; hi.y = y.w;     // keys K0+4..K0+7-> slots d1+8..d1+11
      *(uint2*)(&vtb[rowb + d1])     = lo;
      *(uint2*)(&vtb[rowb + d1 + 8]) = hi;
    }
  }
}

// ---------------- output projection GEMM (64x64 tile, dbuf, pair-row swizzle) ---
__global__ __launch_bounds__(256)
void out_gemm(const u16* __restrict__ A, const u16* __restrict__ Bt,
              const float* __restrict__ bias, float* __restrict__ outf) {
  __shared__ u16 As[2][64 * 32];      // [32 prows][64 elems] pair-row swizzled
  __shared__ u16 Bs[2][64 * 32];
  const int bm = blockIdx.x, bn = blockIdx.y;
  const int tid = threadIdx.x;
  const int wave = tid >> 6, lane = tid & 63;
  const int wm = (wave & 1) * 32, wn = (wave >> 1) * 32;
  const int row = lane & 15, quad = lane >> 4;
  const int e = tid * 8;
  const int p_ = e >> 6, u_ = ((e >> 3) & 7) ^ (p_ & 7);
  const int sr = 2 * p_ + (u_ >> 2), sc = (u_ & 3) * 8;
  const u16* pa = A  + (size_t)(bm * 64 + sr) * DIMC + sc;
  const u16* pb = Bt + (size_t)(bn * 64 + sr) * DIMC + sc;
  int aoff[2], boff[2];
  #pragma unroll
  for (int i = 0; i < 2; ++i) {
    int Ra = wm + i * 16 + row, Pa = Ra >> 1;
    aoff[i] = Pa * 64 + (((((Ra & 1) << 2) | quad) ^ (Pa & 7)) * 8);
    int Rb = wn + i * 16 + row, Pb = Rb >> 1;
    boff[i] = Pb * 64 + (((((Rb & 1) << 2) | quad) ^ (Pb & 7)) * 8);
  }
  f32x4 acc[2][2] = {};
  gload_lds16(pa, &As[0][e]);
  gload_lds16(pb, &Bs[0][e]);
  pa += 32; pb += 32;
  __syncthreads();
  for (int k0 = 0; k0 < DIMC; k0 += 32) {
    const int cur = (k0 >> 5) & 1;
    if (k0 + 32 < DIMC) {              // issue next tile BEFORE compute
      gload_lds16(pa, &As[cur ^ 1][e]);
      gload_lds16(pb, &Bs[cur ^ 1][e]);
      pa += 32; pb += 32;
    }
    bf16x8 a[2], b[2];
    #pragma unroll
    for (int i = 0; i < 2; ++i)
      a[i] = *(const bf16x8*)(&As[cur][aoff[i]]);
    #pragma unroll
    for (int j = 0; j < 2; ++j)
      b[j] = *(const bf16x8*)(&Bs[cur][boff[j]]);
    #pragma unroll
    for (int i = 0; i < 2; ++i)
      #pragma unroll
      for (int j = 0; j < 2; ++j)
        acc[i][j] = __builtin_amdgcn_mfma_f32_16x16x32_bf16(a[i], b[j], acc[i][j], 0, 0, 0);
    __syncthreads();
  }
  #pragma unroll
  for (int i = 0; i < 2; ++i)
    #pragma unroll
    for (int j = 0; j < 2; ++j)
      #pragma unroll
      for (int r = 0; r < 4; ++r) {
        int m = bm * 64 + wm + i * 16 + quad * 4 + r;
        int c = bn * 64 + wn + j * 16 + row;
        outf[(size_t)m * DIMC + c] = acc[i][j][r] + bias[c];
      }
}

// ---------------- fused flash attention, IN-BLOCK KEY-SPLIT x2 (R9, proven) -----
__global__ __launch_bounds__(512)
void attn_fused(const u16* __restrict__ qh, const u16* __restrict__ kh,
                const u16* __restrict__ vt, u16* __restrict__ ao) {
  __shared__ u16 smem[32768];        // 64KB: Ks[half][buf] 4x8KB | Vs[half][buf] 4x8KB
  u16* KS = smem;                    // KS + ((half*2+buf)*4096)
  u16* VS = smem + 16384;
  const int flat = blockIdx.x;
  const int bh = (flat & 7) * 4 + ((flat >> 3) & 3);
  const int qtile = flat >> 5;       // 0..15, 128 q-rows each
  const int b = bh >> 4, h = bh & 15;
  const int tid = threadIdx.x;
  const int wave = tid >> 6, lane = tid & 63;
  const int half = wave >> 2;        // key-split half: 0 or 1
  const int wq = wave & 3;           // q-subwave within half
  const int qi = lane & 15, quad = lane >> 4;
  const int sw = qi & 7;
  const size_t base = (size_t)bh * NSEQ * HD;
  bf16x8 qf[2][2];                   // [q-subtile][d-half]
  #pragma unroll
  for (int qt = 0; qt < 2; ++qt) {
    int qrow = qtile * 128 + wq * 32 + qt * 16 + qi;
    #pragma unroll
    for (int dh = 0; dh < 2; ++dh)
      qf[qt][dh] = *(const bf16x8*)(&qh[base + (size_t)qrow * HD + dh * 32 + quad * 8]);
  }
  // per-thread staging offsets within this half (256 threads per half)
  const int htid = tid & 255;
  const int rk0 = htid >> 3, ck0 = htid & 7;        // chunk rows 0..31
  const int rk1 = 32 + (htid >> 3);                 // chunk rows 32..63
  const int ko0 = rk0 * HD + ((ck0 ^ (rk0 & 7)) * 8);
  const int ko1 = rk1 * HD + ((ck0 ^ (rk1 & 7)) * 8);
  const int vo0 = rk0 * NSEQ + ((ck0 ^ (rk0 & 7)) * 8);
  const int vo1 = rk1 * NSEQ + ((ck0 ^ (rk1 & 7)) * 8);
  const int ldso = htid * 8;
  u16* Kh = KS + half * 8192;        // this half's two buffers
  u16* Vh = VS + half * 8192;
  const u16* kcur = kh + base + (size_t)(half * 1024) * HD;
  const u16* vcur = vt + base + half * 1024;
  // prologue: stage this half's tile 0 into buffer 0
  gload_lds16(kcur + ko0, Kh + ldso);
  gload_lds16(kcur + ko1, Kh + 2048 + ldso);
  gload_lds16(vcur + vo0, Vh + ldso);
  gload_lds16(vcur + vo1, Vh + 2048 + ldso);
  kcur += 64 * HD; vcur += 64;
  __syncthreads();                    // drains vmcnt -> tile 0 resident
  float li0 = 0.f, li1 = 0.f;
  f32x4 oacc[2][4] = {};
  for (int t = 0; t < 16; ++t) {      // 16 x 64-key tiles per half
    const int cur = t & 1;
    if (t < 15) {                     // issue next tile's loads BEFORE compute
      u16* kd = Kh + (cur ^ 1) * 4096;
      u16* vd = Vh + (cur ^ 1) * 4096;
      gload_lds16(kcur + ko0, kd + ldso);
      gload_lds16(kcur + ko1, kd + 2048 + ldso);
      gload_lds16(vcur + vo0, vd + ldso);
      gload_lds16(vcur + vo1, vd + 2048 + ldso);
      kcur += 64 * HD; vcur += 64;
    }
    const u16* Kb = Kh + cur * 4096;
    const u16* Vb = Vh + cur * 4096;
    #pragma unroll
    for (int kc = 0; kc < 2; ++kc) {
      const u16* kr0 = &Kb[((kc * 2) * 16 + qi) * 64];
      const u16* kr1 = &Kb[((kc * 2 + 1) * 16 + qi) * 64];
      bf16x8 ka0 = *(const bf16x8*)(&kr0[(quad ^ sw) * 8]);
      bf16x8 ka1 = *(const bf16x8*)(&kr0[((4 + quad) ^ sw) * 8]);
      bf16x8 kb0 = *(const bf16x8*)(&kr1[(quad ^ sw) * 8]);
      bf16x8 kb1 = *(const bf16x8*)(&kr1[((4 + quad) ^ sw) * 8]);
      bf16x8 vf[4];
      #pragma unroll
      for (int dt = 0; dt < 4; ++dt)
        vf[dt] = *(const bf16x8*)(&Vb[(dt * 16 + qi) * 64 + ((kc * 4 + quad) ^ sw) * 8]);
      f32x4 s00 = {}, s01 = {}, s10 = {}, s11 = {};   // [q-subtile][key-tile]
      __builtin_amdgcn_s_setprio(1);
      s00 = __builtin_amdgcn_mfma_f32_16x16x32_bf16(ka0, qf[0][0], s00, 0, 0, 0);
      s00 = __builtin_amdgcn_mfma_f32_16x16x32_bf16(ka1, qf[0][1], s00, 0, 0, 0);
      s01 = __builtin_amdgcn_mfma_f32_16x16x32_bf16(kb0, qf[0][0], s01, 0, 0, 0);
      s01 = __builtin_amdgcn_mfma_f32_16x16x32_bf16(kb1, qf[0][1], s01, 0, 0, 0);
      s10 = __builtin_amdgcn_mfma_f32_16x16x32_bf16(ka0, qf[1][0], s10, 0, 0, 0);
      s10 = __builtin_amdgcn_mfma_f32_16x16x32_bf16(ka1, qf[1][1], s10, 0, 0, 0);
      s11 = __builtin_amdgcn_mfma_f32_16x16x32_bf16(kb0, qf[1][0], s11, 0, 0, 0);
      s11 = __builtin_amdgcn_mfma_f32_16x16x32_bf16(kb1, qf[1][1], s11, 0, 0, 0);
      __builtin_amdgcn_s_setprio(0);
      float a0 = EXP2(s00[0]), a1 = EXP2(s00[1]), a2 = EXP2(s00[2]), a3 = EXP2(s00[3]);
      float a4 = EXP2(s01[0]), a5 = EXP2(s01[1]), a6 = EXP2(s01[2]), a7 = EXP2(s01[3]);
      float b0 = EXP2(s10[0]), b1 = EXP2(s10[1]), b2 = EXP2(s10[2]), b3 = EXP2(s10[3]);
      float b4 = EXP2(s11[0]), b5 = EXP2(s11[1]), b6 = EXP2(s11[2]), b7 = EXP2(s11[3]);
      li0 += ((a0 + a1) + (a2 + a3)) + ((a4 + a5) + (a6 + a7));
      li1 += ((b0 + b1) + (b2 + b3)) + ((b4 + b5) + (b6 + b7));
      union { bf16x8 v; u32 u[4]; } pu0, pu1;
      pu0.u[0] = pack_trunc(a0, a1); pu0.u[1] = pack_trunc(a2, a3);
      pu0.u[2] = pack_trunc(a4, a5); pu0.u[3] = pack_trunc(a6, a7);
      pu1.u[0] = pack_trunc(b0, b1); pu1.u[1] = pack_trunc(b2, b3);
      pu1.u[2] = pack_trunc(b4, b5); pu1.u[3] = pack_trunc(b6, b7);
      __builtin_amdgcn_s_setprio(1);
      #pragma unroll
      for (int dt = 0; dt < 4; ++dt) {
        oacc[0][dt] = __builtin_amdgcn_mfma_f32_16x16x32_bf16(vf[dt], pu0.v, oacc[0][dt], 0, 0, 0);
        oacc[1][dt] = __builtin_amdgcn_mfma_f32_16x16x32_bf16(vf[dt], pu1.v, oacc[1][dt], 0, 0, 0);
      }
      __builtin_amdgcn_s_setprio(0);
    }
    __syncthreads();                  // all waves done with buf[cur]; next loads drained
  }
  // ---- combine halves through LDS (SoA: comp-major, stride-1 lanes, no conflicts)
  float* cb = (float*)smem;           // 34 comps x 256 idx x 4B = 34.8KB (staging done)
  const int idx = wq * 64 + lane;
  if (half == 1) {
    #pragma unroll
    for (int qt = 0; qt < 2; ++qt)
      #pragma unroll
      for (int dt = 0; dt < 4; ++dt)
        #pragma unroll
        for (int r = 0; r < 4; ++r)
          cb[(qt * 16 + dt * 4 + r) * 256 + idx] = oacc[qt][dt][r];
    cb[32 * 256 + idx] = li0;
    cb[33 * 256 + idx] = li1;
  }
  __syncthreads();
  if (half == 0) {
    #pragma unroll
    for (int qt = 0; qt < 2; ++qt)
      #pragma unroll
      for (int dt = 0; dt < 4; ++dt)
        #pragma unroll
        for (int r = 0; r < 4; ++r)
          oacc[qt][dt][r] += cb[(qt * 16 + dt * 4 + r) * 256 + idx];
    li0 += cb[32 * 256 + idx];
    li1 += cb[33 * 256 + idx];
    // deferred cross-lane softmax-denominator reduction
    li0 += __shfl_xor(li0, 16); li0 += __shfl_xor(li0, 32);
    li1 += __shfl_xor(li1, 16); li1 += __shfl_xor(li1, 32);
    #pragma unroll
    for (int qt = 0; qt < 2; ++qt) {
      float inv = 1.0f / (qt == 0 ? li0 : li1);
      int token = b * NSEQ + qtile * 128 + wq * 32 + qt * 16 + qi;
      #pragma unroll
      for (int dt = 0; dt < 4; ++dt) {
        int col = h * 64 + dt * 16 + quad * 4;
        *(u32*)(&ao[(size_t)token * DIMC + col]) =
            pack_rne(oacc[qt][dt][0] * inv, oacc[qt][dt][1] * inv);
        *(u32*)(&ao[(size_t)token * DIMC + col + 2]) =
            pack_rne(oacc[qt][dt][2] * inv, oacc[qt][dt][3] * inv);
      }
    }
  }
}

extern "C" void kernel_launch(void* const* d_in, const int* in_sizes, int n_in,
                              void* d_out, int out_size, void* d_ws, size_t ws_size,
                              hipStream_t stream) {
  const float* q    = (const float*)d_in[0];
  const float* k    = (const float*)d_in[1];
  const float* v    = (const float*)d_in[2];
  const float* gq   = (const float*)d_in[3];
  const float* bqln = (const float*)d_in[4];
  const float* gk   = (const float*)d_in[5];
  const float* bkln = (const float*)d_in[6];
  const float* gv   = (const float*)d_in[7];
  const float* bvln = (const float*)d_in[8];
  const float* Wq   = (const float*)d_in[9];
  const float* bq   = (const float*)d_in[10];
  const float* Wk   = (const float*)d_in[11];
  const float* bk   = (const float*)d_in[12];
  const float* Wv   = (const float*)d_in[13];
  const float* bv   = (const float*)d_in[14];
  const float* Wp   = (const float*)d_in[15];
  const float* bp   = (const float*)d_in[16];
  float* out = (float*)d_out;

  char* ws = (char*)d_ws;
  u16* xn  = (u16*)(ws);                          // 3 x 4096x1024 bf16 (24MB)
  u16* wt  = (u16*)(ws + (size_t)25165824);       // 4 x 1024x1024 bf16 (8MB)
  u16* qh  = (u16*)(ws + (size_t)33554432);       // [bh][n][d] bf16 (pre-scaled)
  u16* khb = (u16*)(ws + (size_t)41943040);       // [bh][n][d] bf16
  u16* ao  = (u16*)(ws + (size_t)50331648);       // [token][1024] bf16
  // V^T lives in the output-0 region of d_out (16.78 MB, exactly fits);
  // out_gemm overwrites it afterwards.
  u16* vtb = (u16*)d_out;                         // [bh][d][n-permuted] bf16

  const size_t WEL = (size_t)DIMC * DIMC;

  prep<<<3 * MROWS / 4 + 1024, 256, 0, stream>>>(q, k, v, gq, bqln, gk, bkln, gv, bvln,
                                                 Wq, Wk, Wv, Wp, xn, wt);
  qkv_gemm<<<dim3(MROWS / 128, DIMC / 128, 3), 256, 0, stream>>>(
      xn, wt, bq, bk, bv, out, qh, khb, vtb);
  attn_fused<<<dim3((NSEQ / 128) * BATCH * HEADS), 512, 0, stream>>>(qh, khb, vtb, ao);
  out_gemm<<<dim3(MROWS / 64, DIMC / 64), 256, 0, stream>>>(ao, wt + 3 * WEL, bp, out);
}